// Round 6
// baseline (100.102 us; speedup 1.0000x reference)
//
#include <hip/hip_runtime.h>

// PointPillarScatter: out[b][c][y][x] = pf[b][p][c] where coords[b][p] = (b,0,y,x), else 0.
// B=8, P=20000, C=64, NX=432, NY=496. Output (8,64,496,432) fp32.
//
// Gather formulation:
//   K1: map16[b][cell] = 0xFFFF; zrow[0..63] = 0.0f   (ushort map 3.4 MB + 256 B zero row)
//   K2: map16[b][y*NX+x] = p
//   K3: one thread per (b, 4-cell group); loops 16 channel-quads.
//       Invalid cells redirect to zrow -> UNCONDITIONAL loads (no exec masking,
//       low VGPR), __launch_bounds__(64,6) forces >=6 waves/SIMD for latency
//       hiding of the scattered pf reads. Chunked XCD swizzle: one batch/XCD.

#define BB    8
#define PP    20000
#define CC    64
#define NXX   432
#define NYY   496
#define NCELL (NXX * NYY)   /* 214272 */
#define NCELL4 (NCELL / 4)  /* 53568  */

#define GBLK   64
#define GNWG   ((BB * NCELL4) / GBLK)  /* 428544/64 = 6696 exactly */
#define NXCD   8
#define CHUNK  (GNWG / NXCD)           /* 837: exactly one batch per XCD */

#define MAP_INT4S ((BB * NCELL * 2) / 16)  /* 214272 int4s of map */
#define ZROW_INT4S 16                      /* 256 B zero row */

typedef float f32x4 __attribute__((ext_vector_type(4)));
typedef unsigned short u16;
typedef u16 u16x4 __attribute__((ext_vector_type(4)));

__global__ void ppsc_init_ws(int* __restrict__ ws) {
    int t = blockIdx.x * blockDim.x + threadIdx.x;
    if (t < MAP_INT4S + ZROW_INT4S) {
        int v = (t < MAP_INT4S) ? -1 : 0;   // map = 0xFFFF sentinels, zrow = 0.0f
        ((int4*)ws)[t] = make_int4(v, v, v, v);
    }
}

__global__ void ppsc_scatter_map(const int* __restrict__ coords, u16* __restrict__ map16) {
    int t = blockIdx.x * blockDim.x + threadIdx.x;  // one thread per (b,p)
    if (t >= BB * PP) return;
    int b = t / PP;
    int p = t - b * PP;
    const int4 c4 = ((const int4*)coords)[t];       // [b, z, y, x] as int32
    int y = c4.z, x = c4.w;
    if ((unsigned)y < (unsigned)NYY && (unsigned)x < (unsigned)NXX)
        map16[(size_t)b * NCELL + y * NXX + x] = (u16)p;
}

// one thread per (b, cell-quad); all 64 channels.
__global__ void __launch_bounds__(GBLK, 6) ppsc_gather_all(const float* __restrict__ pf,
                                                           const u16* __restrict__ map16,
                                                           const float* __restrict__ zrow,
                                                           float* __restrict__ out) {
    // chunked XCD swizzle: hardware bids round-robin XCDs; remap so XCD k owns
    // contiguous blocks [k*CHUNK,(k+1)*CHUNK) == exactly batch k.
    int bid = blockIdx.x;
    int wg  = (bid % NXCD) * CHUNK + bid / NXCD;

    int t  = wg * GBLK + threadIdx.x;
    int i4 = t % NCELL4;
    int b  = t / NCELL4;

    u16x4 m = ((const u16x4*)(map16 + (size_t)b * NCELL))[i4];
    const float* base = pf + (size_t)b * PP * CC;
    const float* p0 = (m.x != 0xFFFFu) ? base + (size_t)m.x * CC : zrow;
    const float* p1 = (m.y != 0xFFFFu) ? base + (size_t)m.y * CC : zrow;
    const float* p2 = (m.z != 0xFFFFu) ? base + (size_t)m.z * CC : zrow;
    const float* p3 = (m.w != 0xFFFFu) ? base + (size_t)m.w * CC : zrow;

    float* ob = out + (size_t)b * CC * NCELL + (size_t)i4 * 4;

#pragma unroll 2
    for (int cq = 0; cq < 16; ++cq) {
        f32x4 f0 = *(const f32x4*)(p0 + cq * 4);
        f32x4 f1 = *(const f32x4*)(p1 + cq * 4);
        f32x4 f2 = *(const f32x4*)(p2 + cq * 4);
        f32x4 f3 = *(const f32x4*)(p3 + cq * 4);
        f32x4 o0 = {f0.x, f1.x, f2.x, f3.x};
        f32x4 o1 = {f0.y, f1.y, f2.y, f3.y};
        f32x4 o2 = {f0.z, f1.z, f2.z, f3.z};
        f32x4 o3 = {f0.w, f1.w, f2.w, f3.w};
        float* op = ob + (size_t)(cq * 4) * NCELL;
        __builtin_nontemporal_store(o0, (f32x4*)op);
        __builtin_nontemporal_store(o1, (f32x4*)(op + (size_t)NCELL));
        __builtin_nontemporal_store(o2, (f32x4*)(op + 2 * (size_t)NCELL));
        __builtin_nontemporal_store(o3, (f32x4*)(op + 3 * (size_t)NCELL));
    }
}

// ---- fallback path (ws too small): zero output + direct scatter ----
__global__ void ppsc_zero(float* __restrict__ out, int n4) {
    int t = blockIdx.x * blockDim.x + threadIdx.x;
    if (t < n4) ((float4*)out)[t] = make_float4(0.f, 0.f, 0.f, 0.f);
}

__global__ void ppsc_direct_scatter(const float* __restrict__ pf,
                                    const int* __restrict__ coords,
                                    float* __restrict__ out) {
    int t = blockIdx.x * blockDim.x + threadIdx.x;  // one thread per (b,p,c)
    if (t >= BB * PP * CC) return;
    int c  = t % CC;
    int bp = t / CC;
    int b  = bp / PP;
    const int* cd = coords + (size_t)bp * 4;
    int y = cd[2], x = cd[3];
    if ((unsigned)y < (unsigned)NYY && (unsigned)x < (unsigned)NXX)
        out[((size_t)(b * CC + c)) * NCELL + (size_t)y * NXX + x] = pf[(size_t)bp * CC + c];
}

extern "C" void kernel_launch(void* const* d_in, const int* in_sizes, int n_in,
                              void* d_out, int out_size, void* d_ws, size_t ws_size,
                              hipStream_t stream) {
    const float* pf     = (const float*)d_in[0];
    const int*   coords = (const int*)d_in[1];
    float*       out    = (float*)d_out;

    const size_t map_bytes = (size_t)BB * NCELL * sizeof(u16);  // 3.43 MB
    const size_t ws_need   = map_bytes + 256;                   // + zero row

    if (ws_size >= ws_need) {
        u16*   map16 = (u16*)d_ws;
        float* zrow  = (float*)((char*)d_ws + map_bytes);

        int n4 = MAP_INT4S + ZROW_INT4S;
        ppsc_init_ws<<<(n4 + 255) / 256, 256, 0, stream>>>((int*)d_ws);

        int npil = BB * PP;                  // 160000
        ppsc_scatter_map<<<(npil + 255) / 256, 256, 0, stream>>>(coords, map16);

        ppsc_gather_all<<<GNWG, GBLK, 0, stream>>>(pf, map16, zrow, out);
    } else {
        int n4_out = out_size / 4;
        ppsc_zero<<<(n4_out + 255) / 256, 256, 0, stream>>>(out, n4_out);

        int nsc = BB * PP * CC;              // 10,240,000
        ppsc_direct_scatter<<<(nsc + 255) / 256, 256, 0, stream>>>(pf, coords, out);
    }
}